// Round 4
// baseline (1342.544 us; speedup 1.0000x reference)
//
#include <hip/hip_runtime.h>
#include <hip/hip_bf16.h>

typedef __hip_bfloat16 bf16;
typedef __attribute__((ext_vector_type(8))) short short8;
typedef __attribute__((ext_vector_type(4))) float f32x4;

#define B_    2
#define S_    2048
#define HID_  4096
#define NH_   32
#define NKV_  8
#define HD_   128
#define QSTRIDE_ (NH_ * HD_)   // 4096
#define KSTRIDE_ (NKV_ * HD_)  // 1024
#define SCALE_ 0.08838834764831845f

__device__ __forceinline__ short f2bs(float x) {
  bf16 h = __float2bfloat16(x);
  return *reinterpret_cast<short*>(&h);
}

// ---------------------------------------------------------------------------
// C = A @ Bt^T : A (M,K) fp32 row-major, Bt (N,K) bf16 row-major, C bf16.
// 128x128 tile, BK=32, 4 waves. A converted fp32->bf16 in registers during
// staging; LDS layouts identical to the verified all-bf16 gemm_nt.
// ---------------------------------------------------------------------------
__global__ __launch_bounds__(256) void gemm_a32_nt(const float* __restrict__ A,
                                                   const bf16* __restrict__ Bt,
                                                   bf16* __restrict__ C,
                                                   int M, int N, int K) {
  __shared__ __align__(16) bf16 lA[128 * 32];
  __shared__ __align__(16) bf16 lB[128 * 32];
  const int tid  = threadIdx.x;
  const int wave = tid >> 6, lane = tid & 63;
  const int wm = wave >> 1, wn = wave & 1;
  const int quad = lane >> 4, l15 = lane & 15;
  const long m0 = (long)blockIdx.y * 128, n0 = (long)blockIdx.x * 128;
  const int srow = lane >> 2;         // B staging row within 16-row chunk
  const int scol = (lane & 3) * 8;    // B staging col (8 bf16 = 16B)
  const int arow = tid >> 2;          // A staging row within 64-row half
  const int acol = (tid & 3) * 8;
  f32x4 acc[4][4] = {};

  for (int k0 = 0; k0 < K; k0 += 32) {
    float4 a0[2], a1[2];
    short8 rb[2];
#pragma unroll
    for (int p = 0; p < 2; ++p) {
      const float* src = A + (m0 + p * 64 + arow) * (long)K + k0 + acol;
      a0[p] = *(const float4*)src;
      a1[p] = *(const float4*)(src + 4);
    }
#pragma unroll
    for (int i = 0; i < 2; ++i) {
      const int c = wave * 2 + i;
      rb[i] = *(const short8*)(Bt + (n0 + c * 16 + srow) * (long)K + k0 + scol);
    }
    __syncthreads();  // previous tile fully consumed
#pragma unroll
    for (int p = 0; p < 2; ++p) {
      const int row = p * 64 + arow;
      short8 cv;
      cv[0] = f2bs(a0[p].x); cv[1] = f2bs(a0[p].y);
      cv[2] = f2bs(a0[p].z); cv[3] = f2bs(a0[p].w);
      cv[4] = f2bs(a1[p].x); cv[5] = f2bs(a1[p].y);
      cv[6] = f2bs(a1[p].z); cv[7] = f2bs(a1[p].w);
      *(short8*)&lA[row * 32 + acol] = cv;
    }
#pragma unroll
    for (int i = 0; i < 2; ++i) {
      const int c = wave * 2 + i;
      *(short8*)&lB[c * 512 + srow * 32 + scol] = rb[i];
    }
    __syncthreads();
    short8 af[4], bq[4];
#pragma unroll
    for (int t = 0; t < 4; ++t)
      af[t] = *(const short8*)&lA[(wm * 64 + t * 16 + l15) * 32 + quad * 8];
#pragma unroll
    for (int t = 0; t < 4; ++t)
      bq[t] = *(const short8*)&lB[(wn * 64 + t * 16 + l15) * 32 + quad * 8];
#pragma unroll
    for (int tm = 0; tm < 4; ++tm)
#pragma unroll
      for (int tn = 0; tn < 4; ++tn)
        acc[tm][tn] = __builtin_amdgcn_mfma_f32_16x16x32_bf16(
            af[tm], bq[tn], acc[tm][tn], 0, 0, 0);
  }
#pragma unroll
  for (int tm = 0; tm < 4; ++tm)
#pragma unroll
    for (int tn = 0; tn < 4; ++tn)
#pragma unroll
      for (int r = 0; r < 4; ++r) {
        const long row = m0 + wm * 64 + tm * 16 + quad * 4 + r;
        const long col = n0 + wn * 64 + tn * 16 + l15;
        C[row * N + col] = __float2bfloat16(acc[tm][tn][r]);
      }
}

// ---------------------------------------------------------------------------
// All-bf16 inputs, FP32 output (for the O-projection into d_out).
// ---------------------------------------------------------------------------
__global__ __launch_bounds__(256) void gemm_nt_f32(const bf16* __restrict__ A,
                                                   const bf16* __restrict__ Bt,
                                                   float* __restrict__ C,
                                                   int M, int N, int K) {
  __shared__ __align__(16) bf16 lA[128 * 32];
  __shared__ __align__(16) bf16 lB[128 * 32];
  const int tid  = threadIdx.x;
  const int wave = tid >> 6, lane = tid & 63;
  const int wm = wave >> 1, wn = wave & 1;
  const int quad = lane >> 4, l15 = lane & 15;
  const long m0 = (long)blockIdx.y * 128, n0 = (long)blockIdx.x * 128;
  const int srow = lane >> 2, scol = (lane & 3) * 8;
  f32x4 acc[4][4] = {};

  for (int k0 = 0; k0 < K; k0 += 32) {
    short8 ra[2], rb[2];
#pragma unroll
    for (int i = 0; i < 2; ++i) {
      const int c = wave * 2 + i;
      ra[i] = *(const short8*)(A  + (m0 + c * 16 + srow) * (long)K + k0 + scol);
      rb[i] = *(const short8*)(Bt + (n0 + c * 16 + srow) * (long)K + k0 + scol);
    }
    __syncthreads();
#pragma unroll
    for (int i = 0; i < 2; ++i) {
      const int c = wave * 2 + i;
      *(short8*)&lA[c * 512 + srow * 32 + scol] = ra[i];
      *(short8*)&lB[c * 512 + srow * 32 + scol] = rb[i];
    }
    __syncthreads();
    short8 af[4], bq[4];
#pragma unroll
    for (int t = 0; t < 4; ++t)
      af[t] = *(const short8*)&lA[(wm * 64 + t * 16 + l15) * 32 + quad * 8];
#pragma unroll
    for (int t = 0; t < 4; ++t)
      bq[t] = *(const short8*)&lB[(wn * 64 + t * 16 + l15) * 32 + quad * 8];
#pragma unroll
    for (int tm = 0; tm < 4; ++tm)
#pragma unroll
      for (int tn = 0; tn < 4; ++tn)
        acc[tm][tn] = __builtin_amdgcn_mfma_f32_16x16x32_bf16(
            af[tm], bq[tn], acc[tm][tn], 0, 0, 0);
  }
#pragma unroll
  for (int tm = 0; tm < 4; ++tm)
#pragma unroll
    for (int tn = 0; tn < 4; ++tn)
#pragma unroll
      for (int r = 0; r < 4; ++r) {
        const long row = m0 + wm * 64 + tm * 16 + quad * 4 + r;
        const long col = n0 + wn * 64 + tn * 16 + l15;
        C[row * N + col] = acc[tm][tn][r];   // fp32 store
      }
}

// ---------------------------------------------------------------------------
// out bf16 (cols, rows) = convert(in fp32 (rows, cols)) transposed.
// ---------------------------------------------------------------------------
__global__ void transpose_f32_bf16(const float* __restrict__ in,
                                   bf16* __restrict__ out, int rows, int cols) {
  __shared__ bf16 t[32][33];
  const int c0 = blockIdx.x * 32, r0 = blockIdx.y * 32;
  const int tx = threadIdx.x, ty = threadIdx.y;
#pragma unroll
  for (int i = 0; i < 4; ++i)
    t[ty + i * 8][tx] =
        __float2bfloat16(in[(long)(r0 + ty + i * 8) * cols + c0 + tx]);
  __syncthreads();
#pragma unroll
  for (int i = 0; i < 4; ++i)
    out[(long)(c0 + ty + i * 8) * rows + r0 + tx] = t[tx][ty + i * 8];
}

// V (b,s,kv,d) bf16 -> VT (b,kv,d,s) bf16
__global__ void v_transpose(const bf16* __restrict__ V, bf16* __restrict__ VT) {
  __shared__ bf16 t[32][33];
  const int z = blockIdx.z;              // b*8+kv
  const int b = z >> 3, kv = z & 7;
  const int d0 = blockIdx.x * 32, s0 = blockIdx.y * 32;
  const int tx = threadIdx.x, ty = threadIdx.y;
#pragma unroll
  for (int i = 0; i < 4; ++i)
    t[ty + i * 8][tx] =
        V[(long)(b * S_ + s0 + ty + i * 8) * KSTRIDE_ + kv * HD_ + d0 + tx];
  __syncthreads();
#pragma unroll
  for (int i = 0; i < 4; ++i)
    VT[((long)z * HD_ + d0 + ty + i * 8) * S_ + s0 + tx] = t[tx][ty + i * 8];
}

// RoPE in-place on bf16 (B*S, nheads*128); cos/sin fp32.
__global__ void rope_kernel(bf16* __restrict__ x, const float* __restrict__ cosb,
                            const float* __restrict__ sinb, int nheads) {
  const int idx = blockIdx.x * blockDim.x + threadIdx.x;
  const int d  = idx & 63;
  const int h  = (idx >> 6) % nheads;
  const int bs = idx / (64 * nheads);
  if (bs >= B_ * S_) return;
  const long base = (long)bs * nheads * HD_ + h * HD_;
  const float x1 = __bfloat162float(x[base + d]);
  const float x2 = __bfloat162float(x[base + d + 64]);
  const float c1 = cosb[(long)bs * HD_ + d];
  const float c2 = cosb[(long)bs * HD_ + d + 64];
  const float s1 = sinb[(long)bs * HD_ + d];
  const float s2 = sinb[(long)bs * HD_ + d + 64];
  x[base + d]      = __float2bfloat16(x1 * c1 - x2 * s1);
  x[base + d + 64] = __float2bfloat16(x2 * c2 + x1 * s2);
}

// ---------------------------------------------------------------------------
// Flash attention, causal, GQA. BM=64 q rows/block (4 waves x 16), BN=64 kv.
// Q (b,s,h,d), K (b,s,kv,d), VT (b,kv,d,s) -> ctx (b,s,h,d). All bf16.
// LDS tiles chunked-32: elem(row,k) at [k/32][row][k%32]. Explicit staging.
// ---------------------------------------------------------------------------
__global__ __launch_bounds__(256) void attn_fwd(const bf16* __restrict__ Q,
                                                const bf16* __restrict__ Kc,
                                                const bf16* __restrict__ VT,
                                                bf16* __restrict__ ctx) {
  __shared__ __align__(16) bf16 lQ[64 * 128];
  __shared__ __align__(16) bf16 lK[64 * 128];
  __shared__ __align__(16) bf16 lV[128 * 64];
  __shared__ __align__(16) bf16 lP[64 * 64];
  const int tid  = threadIdx.x;
  const int wave = tid >> 6, lane = tid & 63;
  const int quad = lane >> 4, l15 = lane & 15;
  const int srow = lane >> 2, scol = (lane & 3) * 8;
  const int qt = blockIdx.x, bh = blockIdx.y;
  const int b = bh >> 5, h = bh & 31, kv = h >> 2;
  const int q0 = qt * 64;
  const long qbase = (long)b * S_ * QSTRIDE_ + h * HD_;
  const long kbase = (long)b * S_ * KSTRIDE_ + kv * HD_;
  const long vbase = (long)(b * NKV_ + kv) * HD_ * S_;

#pragma unroll
  for (int i = 0; i < 4; ++i) {
    const int c = wave * 4 + i;
    const int slab = c >> 2;
    const int row  = (c & 3) * 16 + srow;
    const int col  = slab * 32 + scol;
    *(short8*)&lQ[c * 512 + srow * 32 + scol] =
        *(const short8*)(Q + qbase + (long)(q0 + row) * QSTRIDE_ + col);
  }

  float m_i[4] = {-1e30f, -1e30f, -1e30f, -1e30f};
  float l_i[4] = {0.f, 0.f, 0.f, 0.f};
  f32x4 o[8] = {};

  const int nkt = qt + 1;
  for (int kt = 0; kt < nkt; ++kt) {
    const int k0 = kt * 64;
    short8 rk[4], rv[4];
#pragma unroll
    for (int i = 0; i < 4; ++i) {
      const int c = wave * 4 + i;
      {
        const int row = (c & 3) * 16 + srow;
        const int col = (c >> 2) * 32 + scol;
        rk[i] = *(const short8*)(Kc + kbase + (long)(k0 + row) * KSTRIDE_ + col);
      }
      {
        const int row = (c & 7) * 16 + srow;
        const int col = (c >> 3) * 32 + scol;
        rv[i] = *(const short8*)(VT + vbase + (long)row * S_ + k0 + col);
      }
    }
    __syncthreads();
#pragma unroll
    for (int i = 0; i < 4; ++i) {
      const int c = wave * 4 + i;
      *(short8*)&lK[c * 512 + srow * 32 + scol] = rk[i];
      *(short8*)&lV[c * 512 + srow * 32 + scol] = rv[i];
    }
    __syncthreads();

    f32x4 sc[4] = {};
#pragma unroll
    for (int kc = 0; kc < 4; ++kc) {
      const short8 a = *(const short8*)&lQ[kc * 2048 + (wave * 16 + l15) * 32 + quad * 8];
#pragma unroll
      for (int j = 0; j < 4; ++j) {
        const short8 bb = *(const short8*)&lK[kc * 2048 + (j * 16 + l15) * 32 + quad * 8];
        sc[j] = __builtin_amdgcn_mfma_f32_16x16x32_bf16(a, bb, sc[j], 0, 0, 0);
      }
    }

#pragma unroll
    for (int r = 0; r < 4; ++r) {
      const int qg = q0 + wave * 16 + quad * 4 + r;
      float mx = -1e30f;
#pragma unroll
      for (int j = 0; j < 4; ++j) {
        float s = sc[j][r] * SCALE_;
        const int kg = k0 + j * 16 + l15;
        if (kg > qg) s = -1e9f;
        sc[j][r] = s;
        mx = fmaxf(mx, s);
      }
#pragma unroll
      for (int off = 1; off < 16; off <<= 1)
        mx = fmaxf(mx, __shfl_xor(mx, off, 64));
      const float mn = fmaxf(m_i[r], mx);
      const float alpha = __expf(m_i[r] - mn);
      float rs = 0.f;
#pragma unroll
      for (int j = 0; j < 4; ++j) {
        const float p = __expf(sc[j][r] - mn);
        sc[j][r] = p;
        rs += p;
      }
#pragma unroll
      for (int off = 1; off < 16; off <<= 1)
        rs += __shfl_xor(rs, off, 64);
      m_i[r] = mn;
      l_i[r] = l_i[r] * alpha + rs;
#pragma unroll
      for (int n = 0; n < 8; ++n) o[n][r] *= alpha;
      const int rloc = wave * 16 + quad * 4 + r;
#pragma unroll
      for (int j = 0; j < 4; ++j) {
        const int col = j * 16 + l15;
        lP[(col >> 5) * 2048 + rloc * 32 + (col & 31)] = __float2bfloat16(sc[j][r]);
      }
    }
    __syncthreads();

#pragma unroll
    for (int kc = 0; kc < 2; ++kc) {
      const short8 a = *(const short8*)&lP[kc * 2048 + (wave * 16 + l15) * 32 + quad * 8];
#pragma unroll
      for (int n = 0; n < 8; ++n) {
        const short8 bb = *(const short8*)&lV[kc * 4096 + (n * 16 + l15) * 32 + quad * 8];
        o[n] = __builtin_amdgcn_mfma_f32_16x16x32_bf16(a, bb, o[n], 0, 0, 0);
      }
    }
  }

#pragma unroll
  for (int r = 0; r < 4; ++r) {
    const int qg = q0 + wave * 16 + quad * 4 + r;
    const float inv = 1.f / l_i[r];
#pragma unroll
    for (int n = 0; n < 8; ++n)
      ctx[qbase + (long)qg * QSTRIDE_ + n * 16 + l15] =
          __float2bfloat16(o[n][r] * inv);
  }
}

// ---------------------------------------------------------------------------
// Workspace: 40M bf16 elems = 80 MiB. Q borrows d_out (64 MiB fp32 buffer;
// Q needs 32 MiB bf16, dead before the final GEMM writes fp32 output).
//   slotT [0, 16M)   : wqT -> wkT -> wvT -> woT (sequential)
//   ctx   [16M, 32M) : Vb (first 4M, transient) -> ctx
//   Kb    [32M, 36M)
//   VTb   [36M, 40M)
// ---------------------------------------------------------------------------
extern "C" void kernel_launch(void* const* d_in, const int* in_sizes, int n_in,
                              void* d_out, int out_size, void* d_ws, size_t ws_size,
                              hipStream_t stream) {
  const float* hidden = (const float*)d_in[0];
  const float* cosb   = (const float*)d_in[1];
  const float* sinb   = (const float*)d_in[2];
  // d_in[3] attention_mask: pure causal triu(-1e9), computed analytically
  const float* wq = (const float*)d_in[4];
  const float* wk = (const float*)d_in[5];
  const float* wv = (const float*)d_in[6];
  const float* wo = (const float*)d_in[7];

  bf16* ws    = (bf16*)d_ws;
  bf16* slotT = ws;                  // 16,777,216 elems
  bf16* ctx   = ws + 16777216;       // 16,777,216
  bf16* Vb    = ctx;                 // transient overlay (4,194,304)
  bf16* Kb    = ws + 33554432;       //  4,194,304
  bf16* VTb   = ws + 37748736;       //  4,194,304
  bf16* Qb    = (bf16*)d_out;        // scratch in d_out; dead before final GEMM
  float* out  = (float*)d_out;       // fp32 output per reference dtype

  const dim3 tb(32, 8);

  transpose_f32_bf16<<<dim3(128, 128), tb, 0, stream>>>(wq, slotT, HID_, QSTRIDE_);
  gemm_a32_nt<<<dim3(32, 32), 256, 0, stream>>>(hidden, slotT, Qb, B_ * S_, QSTRIDE_, HID_);

  transpose_f32_bf16<<<dim3(32, 128), tb, 0, stream>>>(wk, slotT, HID_, KSTRIDE_);
  gemm_a32_nt<<<dim3(8, 32), 256, 0, stream>>>(hidden, slotT, Kb, B_ * S_, KSTRIDE_, HID_);

  transpose_f32_bf16<<<dim3(32, 128), tb, 0, stream>>>(wv, slotT, HID_, KSTRIDE_);
  gemm_a32_nt<<<dim3(8, 32), 256, 0, stream>>>(hidden, slotT, Vb, B_ * S_, KSTRIDE_, HID_);

  rope_kernel<<<(B_ * S_ * NH_ * 64) / 256, 256, 0, stream>>>(Qb, cosb, sinb, NH_);
  rope_kernel<<<(B_ * S_ * NKV_ * 64) / 256, 256, 0, stream>>>(Kb, cosb, sinb, NKV_);

  v_transpose<<<dim3(4, 64, B_ * NKV_), tb, 0, stream>>>(Vb, VTb);

  attn_fwd<<<dim3(S_ / 64, B_ * NH_), 256, 0, stream>>>(Qb, Kb, VTb, ctx);

  transpose_f32_bf16<<<dim3(128, 128), tb, 0, stream>>>(wo, slotT, QSTRIDE_, HID_);
  gemm_nt_f32<<<dim3(32, 32), 256, 0, stream>>>(ctx, slotT, out, B_ * S_, HID_, HID_);
}

// Round 5
// 967.542 us; speedup vs baseline: 1.3876x; 1.3876x over previous
//
#include <hip/hip_runtime.h>
#include <hip/hip_bf16.h>

typedef __hip_bfloat16 bf16;
typedef __attribute__((ext_vector_type(8))) short short8;
typedef __attribute__((ext_vector_type(4))) float f32x4;

#define B_    2
#define S_    2048
#define HID_  4096
#define NH_   32
#define NKV_  8
#define HD_   128
#define QSTRIDE_ (NH_ * HD_)   // 4096
#define KVSTR_   2048          // fused KV row stride
#define SCALE_ 0.08838834764831845f

// async global->LDS, 16B/lane; LDS dest = wave-uniform base + lane*16
__device__ __forceinline__ void lds_cp16(void* lds, const void* g) {
  __builtin_amdgcn_global_load_lds(
      (const __attribute__((address_space(1))) void*)g,
      (__attribute__((address_space(3))) void*)lds, 16, 0, 0);
}

// ---------------------------------------------------------------------------
// fp32 -> bf16 elementwise convert (hidden pre-pass). 8 elems/thread.
// ---------------------------------------------------------------------------
__global__ void cvt_f32_bf16(const float* __restrict__ in, bf16* __restrict__ out,
                             long n) {
  const long i = ((long)blockIdx.x * blockDim.x + threadIdx.x) * 8;
  if (i >= n) return;
  float4 a = *(const float4*)(in + i);
  float4 b = *(const float4*)(in + i + 4);
  short8 cv;
  bf16 h;
  h = __float2bfloat16(a.x); cv[0] = *(short*)&h;
  h = __float2bfloat16(a.y); cv[1] = *(short*)&h;
  h = __float2bfloat16(a.z); cv[2] = *(short*)&h;
  h = __float2bfloat16(a.w); cv[3] = *(short*)&h;
  h = __float2bfloat16(b.x); cv[4] = *(short*)&h;
  h = __float2bfloat16(b.y); cv[5] = *(short*)&h;
  h = __float2bfloat16(b.z); cv[6] = *(short*)&h;
  h = __float2bfloat16(b.w); cv[7] = *(short*)&h;
  *(short8*)(out + i) = cv;
}

// ---------------------------------------------------------------------------
// C = A @ Bt^T, all bf16, m97 structure: 128x128 tile, BK=32, 4 waves,
// global_load_lds width 16.
// ---------------------------------------------------------------------------
__global__ __launch_bounds__(256) void gemm_nt(const bf16* __restrict__ A,
                                               const bf16* __restrict__ Bt,
                                               bf16* __restrict__ C,
                                               int M, int N, int K) {
  __shared__ __align__(16) bf16 lA[128 * 32];
  __shared__ __align__(16) bf16 lB[128 * 32];
  const int tid  = threadIdx.x;
  const int wave = tid >> 6, lane = tid & 63;
  const int wm = wave >> 1, wn = wave & 1;
  const int quad = lane >> 4, l15 = lane & 15;
  const long m0 = (long)blockIdx.y * 128, n0 = (long)blockIdx.x * 128;
  const int srow = lane >> 2, scol = (lane & 3) * 8;
  f32x4 acc[4][4] = {};

  for (int k0 = 0; k0 < K; k0 += 32) {
    __syncthreads();
#pragma unroll
    for (int i = 0; i < 2; ++i) {
      const int c = wave * 2 + i;
      lds_cp16(&lA[c * 512], A  + (m0 + c * 16 + srow) * (long)K + k0 + scol);
      lds_cp16(&lB[c * 512], Bt + (n0 + c * 16 + srow) * (long)K + k0 + scol);
    }
    __syncthreads();
    short8 af[4], bq[4];
#pragma unroll
    for (int t = 0; t < 4; ++t)
      af[t] = *(const short8*)&lA[(wm * 64 + t * 16 + l15) * 32 + quad * 8];
#pragma unroll
    for (int t = 0; t < 4; ++t)
      bq[t] = *(const short8*)&lB[(wn * 64 + t * 16 + l15) * 32 + quad * 8];
#pragma unroll
    for (int tm = 0; tm < 4; ++tm)
#pragma unroll
      for (int tn = 0; tn < 4; ++tn)
        acc[tm][tn] = __builtin_amdgcn_mfma_f32_16x16x32_bf16(
            af[tm], bq[tn], acc[tm][tn], 0, 0, 0);
  }
#pragma unroll
  for (int tm = 0; tm < 4; ++tm)
#pragma unroll
    for (int tn = 0; tn < 4; ++tn)
#pragma unroll
      for (int r = 0; r < 4; ++r) {
        const long row = m0 + wm * 64 + tm * 16 + quad * 4 + r;
        const long col = n0 + wn * 64 + tn * 16 + l15;
        C[row * N + col] = __float2bfloat16(acc[tm][tn][r]);
      }
}

// Same, fp32 output (O-projection into d_out).
__global__ __launch_bounds__(256) void gemm_nt_f32(const bf16* __restrict__ A,
                                                   const bf16* __restrict__ Bt,
                                                   float* __restrict__ C,
                                                   int M, int N, int K) {
  __shared__ __align__(16) bf16 lA[128 * 32];
  __shared__ __align__(16) bf16 lB[128 * 32];
  const int tid  = threadIdx.x;
  const int wave = tid >> 6, lane = tid & 63;
  const int wm = wave >> 1, wn = wave & 1;
  const int quad = lane >> 4, l15 = lane & 15;
  const long m0 = (long)blockIdx.y * 128, n0 = (long)blockIdx.x * 128;
  const int srow = lane >> 2, scol = (lane & 3) * 8;
  f32x4 acc[4][4] = {};

  for (int k0 = 0; k0 < K; k0 += 32) {
    __syncthreads();
#pragma unroll
    for (int i = 0; i < 2; ++i) {
      const int c = wave * 2 + i;
      lds_cp16(&lA[c * 512], A  + (m0 + c * 16 + srow) * (long)K + k0 + scol);
      lds_cp16(&lB[c * 512], Bt + (n0 + c * 16 + srow) * (long)K + k0 + scol);
    }
    __syncthreads();
    short8 af[4], bq[4];
#pragma unroll
    for (int t = 0; t < 4; ++t)
      af[t] = *(const short8*)&lA[(wm * 64 + t * 16 + l15) * 32 + quad * 8];
#pragma unroll
    for (int t = 0; t < 4; ++t)
      bq[t] = *(const short8*)&lB[(wn * 64 + t * 16 + l15) * 32 + quad * 8];
#pragma unroll
    for (int tm = 0; tm < 4; ++tm)
#pragma unroll
      for (int tn = 0; tn < 4; ++tn)
        acc[tm][tn] = __builtin_amdgcn_mfma_f32_16x16x32_bf16(
            af[tm], bq[tn], acc[tm][tn], 0, 0, 0);
  }
#pragma unroll
  for (int tm = 0; tm < 4; ++tm)
#pragma unroll
    for (int tn = 0; tn < 4; ++tn)
#pragma unroll
      for (int r = 0; r < 4; ++r) {
        const long row = m0 + wm * 64 + tm * 16 + quad * 4 + r;
        const long col = n0 + wn * 64 + tn * 16 + l15;
        C[row * N + col] = acc[tm][tn][r];
      }
}

// ---------------------------------------------------------------------------
// out bf16 (cols, rows) = convert(in fp32 (rows, cols)) transposed.
// ---------------------------------------------------------------------------
__global__ void transpose_f32_bf16(const float* __restrict__ in,
                                   bf16* __restrict__ out, int rows, int cols) {
  __shared__ bf16 t[32][33];
  const int c0 = blockIdx.x * 32, r0 = blockIdx.y * 32;
  const int tx = threadIdx.x, ty = threadIdx.y;
#pragma unroll
  for (int i = 0; i < 4; ++i)
    t[ty + i * 8][tx] =
        __float2bfloat16(in[(long)(r0 + ty + i * 8) * cols + c0 + tx]);
  __syncthreads();
#pragma unroll
  for (int i = 0; i < 4; ++i)
    out[(long)(c0 + ty + i * 8) * rows + r0 + tx] = t[tx][ty + i * 8];
}

// V part of fused KV (b,s,[K|V]) -> VT (b,kv,d,s)
__global__ void v_transpose(const bf16* __restrict__ KV, bf16* __restrict__ VT) {
  __shared__ bf16 t[32][33];
  const int z = blockIdx.z;              // b*8+kv
  const int b = z >> 3, kv = z & 7;
  const int d0 = blockIdx.x * 32, s0 = blockIdx.y * 32;
  const int tx = threadIdx.x, ty = threadIdx.y;
#pragma unroll
  for (int i = 0; i < 4; ++i)
    t[ty + i * 8][tx] =
        KV[(long)(b * S_ + s0 + ty + i * 8) * KVSTR_ + 1024 + kv * HD_ + d0 + tx];
  __syncthreads();
#pragma unroll
  for (int i = 0; i < 4; ++i)
    VT[((long)z * HD_ + d0 + ty + i * 8) * S_ + s0 + tx] = t[tx][ty + i * 8];
}

// RoPE in-place on bf16 rows of given stride; cos/sin fp32.
__global__ void rope_kernel(bf16* __restrict__ x, const float* __restrict__ cosb,
                            const float* __restrict__ sinb, int nheads, int stride) {
  const int idx = blockIdx.x * blockDim.x + threadIdx.x;
  const int d  = idx & 63;
  const int h  = (idx >> 6) % nheads;
  const int bs = idx / (64 * nheads);
  if (bs >= B_ * S_) return;
  const long base = (long)bs * stride + h * HD_;
  const float x1 = __bfloat162float(x[base + d]);
  const float x2 = __bfloat162float(x[base + d + 64]);
  const float c1 = cosb[(long)bs * HD_ + d];
  const float c2 = cosb[(long)bs * HD_ + d + 64];
  const float s1 = sinb[(long)bs * HD_ + d];
  const float s2 = sinb[(long)bs * HD_ + d + 64];
  x[base + d]      = __float2bfloat16(x1 * c1 - x2 * s1);
  x[base + d + 64] = __float2bfloat16(x2 * c2 + x1 * s2);
}

// ---------------------------------------------------------------------------
// Flash attention v2: BM=128 q rows/block (32/wave), BN=64 kv, Q in registers,
// no-max softmax (shift-invariance; |s·scale| ~ O(10), fp32-safe), deferred
// l-reduction, global_load_lds staging, reversed qt order (heavy first).
// Q (b,s,h,d) s4096; K = fused KV (b,s,2048); VT (b,kv,d,s) -> ctx (b,s,h,d).
// ---------------------------------------------------------------------------
__global__ __launch_bounds__(256, 2) void attn_fwd(const bf16* __restrict__ Q,
                                                   const bf16* __restrict__ KV,
                                                   const bf16* __restrict__ VT,
                                                   bf16* __restrict__ ctx) {
  __shared__ __align__(16) bf16 lK[64 * 128];   // 4 slabs of 64x32 (rows = kv)
  __shared__ __align__(16) bf16 lV[128 * 64];   // 2 slabs of 128x32 (rows = d)
  __shared__ __align__(16) bf16 lP[128 * 64];   // 2 slabs of 128x32 (rows = q)
  const int tid  = threadIdx.x;
  const int wave = tid >> 6, lane = tid & 63;
  const int quad = lane >> 4, l15 = lane & 15;
  const int srow = lane >> 2, scol = (lane & 3) * 8;
  const int qt = 15 - blockIdx.x, bh = blockIdx.y;
  const int b = bh >> 5, h = bh & 31, kv = h >> 2;
  const int q0 = qt * 128;
  const long qbase = (long)b * S_ * QSTRIDE_ + h * HD_;
  const long kbase = (long)b * S_ * KVSTR_ + kv * HD_;
  const long vbase = (long)(b * NKV_ + kv) * HD_ * S_;

  // Q fragments in registers: wave covers rows [wave*32, wave*32+32)
  short8 qf[2][4];
#pragma unroll
  for (int mi = 0; mi < 2; ++mi)
#pragma unroll
    for (int kc = 0; kc < 4; ++kc)
      qf[mi][kc] = *(const short8*)(
          Q + qbase + (long)(q0 + wave * 32 + mi * 16 + l15) * QSTRIDE_ +
          kc * 32 + quad * 8);

  float lp[2][4] = {};   // per-lane partial row-sums (mi, r)
  f32x4 o[2][8] = {};

  const int nkt = 2 * qt + 2;  // kv tiles 0 .. (q0+127)/64
  for (int kt = 0; kt < nkt; ++kt) {
    const int k0 = kt * 64;
    __syncthreads();  // prev iter fully consumed lK/lV
#pragma unroll
    for (int i = 0; i < 4; ++i) {
      const int c = wave * 4 + i;
      lds_cp16(&lK[c * 512],
               KV + kbase + (long)(k0 + (c & 3) * 16 + srow) * KVSTR_ +
               (c >> 2) * 32 + scol);
      lds_cp16(&lV[c * 512],
               VT + vbase + (long)((c & 7) * 16 + srow) * S_ + k0 +
               (c >> 3) * 32 + scol);
    }
    __syncthreads();

    // S = Q K^T : 32 q rows per wave x 64 kv cols
    f32x4 sc[2][4] = {};
#pragma unroll
    for (int kc = 0; kc < 4; ++kc) {
      short8 kb[4];
#pragma unroll
      for (int j = 0; j < 4; ++j)
        kb[j] = *(const short8*)&lK[kc * 2048 + (j * 16 + l15) * 32 + quad * 8];
#pragma unroll
      for (int mi = 0; mi < 2; ++mi)
#pragma unroll
        for (int j = 0; j < 4; ++j)
          sc[mi][j] = __builtin_amdgcn_mfma_f32_16x16x32_bf16(
              qf[mi][kc], kb[j], sc[mi][j], 0, 0, 0);
    }

    // no-max softmax: p = mask ? 0 : exp(s*scale); accumulate per-lane l.
#pragma unroll
    for (int mi = 0; mi < 2; ++mi)
#pragma unroll
      for (int r = 0; r < 4; ++r) {
        const int qg = q0 + wave * 32 + mi * 16 + quad * 4 + r;
        const int rloc = wave * 32 + mi * 16 + quad * 4 + r;
#pragma unroll
        for (int j = 0; j < 4; ++j) {
          const int kg = k0 + j * 16 + l15;
          const float p = (kg <= qg) ? __expf(sc[mi][j][r] * SCALE_) : 0.f;
          lp[mi][r] += p;
          const int col = j * 16 + l15;
          lP[(col >> 5) * 4096 + rloc * 32 + (col & 31)] = __float2bfloat16(p);
        }
      }
    __syncthreads();  // P visible; lV still valid (overwritten after next top sync)

    // O += P @ V
#pragma unroll
    for (int kc = 0; kc < 2; ++kc) {
      short8 pa[2];
#pragma unroll
      for (int mi = 0; mi < 2; ++mi)
        pa[mi] = *(const short8*)&lP[kc * 4096 + (wave * 32 + mi * 16 + l15) * 32 + quad * 8];
#pragma unroll
      for (int n = 0; n < 8; ++n) {
        const short8 vb = *(const short8*)&lV[kc * 4096 + (n * 16 + l15) * 32 + quad * 8];
#pragma unroll
        for (int mi = 0; mi < 2; ++mi)
          o[mi][n] = __builtin_amdgcn_mfma_f32_16x16x32_bf16(
              pa[mi], vb, o[mi][n], 0, 0, 0);
      }
    }
  }

  // epilogue: reduce l across the 16 lanes sharing each row, then O/l -> ctx
#pragma unroll
  for (int mi = 0; mi < 2; ++mi)
#pragma unroll
    for (int r = 0; r < 4; ++r) {
      float l = lp[mi][r];
#pragma unroll
      for (int off = 1; off < 16; off <<= 1)
        l += __shfl_xor(l, off, 64);
      const float inv = 1.f / l;
      const long row = q0 + wave * 32 + mi * 16 + quad * 4 + r;
#pragma unroll
      for (int n = 0; n < 8; ++n)
        ctx[qbase + row * QSTRIDE_ + n * 16 + l15] =
            __float2bfloat16(o[mi][n][r] * inv);
    }
}

// ---------------------------------------------------------------------------
// Buffers (ws = 40M bf16 elems = 80 MiB, same budget as the passing round):
//   d_out (32M bf16 slots): hiddenB [0,16M) ; Qb [16M,32M) — both dead
//                            before the final fp32 GEMM overwrites d_out.
//   ws: slotT [0,16M): wqT -> wkvT(8M, + VTb overlay at [8M,12M)) -> woT
//       ctx   [16M,32M) ; KVb [32M,40M)
// ---------------------------------------------------------------------------
extern "C" void kernel_launch(void* const* d_in, const int* in_sizes, int n_in,
                              void* d_out, int out_size, void* d_ws, size_t ws_size,
                              hipStream_t stream) {
  const float* hidden = (const float*)d_in[0];
  const float* cosb   = (const float*)d_in[1];
  const float* sinb   = (const float*)d_in[2];
  // d_in[3] attention_mask: pure causal triu(-1e9), computed analytically
  const float* wq = (const float*)d_in[4];
  const float* wk = (const float*)d_in[5];
  const float* wv = (const float*)d_in[6];
  const float* wo = (const float*)d_in[7];

  bf16* ws      = (bf16*)d_ws;
  bf16* slotT   = ws;                  // 16M elems
  bf16* VTb     = ws + 8388608;        // overlay in slotT tail (4M)
  bf16* ctx     = ws + 16777216;       // 16M
  bf16* KVb     = ws + 33554432;       //  8M
  bf16* hiddenB = (bf16*)d_out;        // 16M (scratch in d_out)
  bf16* Qb      = (bf16*)d_out + 16777216;  // 16M (scratch in d_out)
  float* out    = (float*)d_out;

  const dim3 tb(32, 8);

  cvt_f32_bf16<<<8192, 256, 0, stream>>>(hidden, hiddenB, (long)B_ * S_ * HID_);

  // Q projection
  transpose_f32_bf16<<<dim3(128, 128), tb, 0, stream>>>(wq, slotT, HID_, QSTRIDE_);
  gemm_nt<<<dim3(32, 32), 256, 0, stream>>>(hiddenB, slotT, Qb, B_ * S_, QSTRIDE_, HID_);

  // fused K|V projection (N = 2048)
  transpose_f32_bf16<<<dim3(32, 128), tb, 0, stream>>>(wk, slotT, HID_, 1024);
  transpose_f32_bf16<<<dim3(32, 128), tb, 0, stream>>>(wv, slotT + 1024 * HID_, HID_, 1024);
  gemm_nt<<<dim3(16, 32), 256, 0, stream>>>(hiddenB, slotT, KVb, B_ * S_, KVSTR_, HID_);

  rope_kernel<<<(B_ * S_ * NH_ * 64) / 256, 256, 0, stream>>>(Qb, cosb, sinb, NH_, QSTRIDE_);
  rope_kernel<<<(B_ * S_ * NKV_ * 64) / 256, 256, 0, stream>>>(KVb, cosb, sinb, NKV_, KVSTR_);

  v_transpose<<<dim3(4, 64, B_ * NKV_), tb, 0, stream>>>(KVb, VTb);

  attn_fwd<<<dim3(16, B_ * NH_), 256, 0, stream>>>(Qb, KVb, VTb, ctx);

  // O projection (fp32 out)
  transpose_f32_bf16<<<dim3(128, 128), tb, 0, stream>>>(wo, slotT, QSTRIDE_, HID_);
  gemm_nt_f32<<<dim3(32, 32), 256, 0, stream>>>(ctx, slotT, out, B_ * S_, HID_, HID_);
}

// Round 6
// 854.134 us; speedup vs baseline: 1.5718x; 1.1328x over previous
//
#include <hip/hip_runtime.h>
#include <hip/hip_bf16.h>

typedef __hip_bfloat16 bf16;
typedef __attribute__((ext_vector_type(8))) short short8;
typedef __attribute__((ext_vector_type(4))) float f32x4;

#define B_    2
#define S_    2048
#define HID_  4096
#define NH_   32
#define NKV_  8
#define HD_   128
#define QSTRIDE_ (NH_ * HD_)   // 4096 (ctx stride)
#define QKVSTR_  6144          // fused Q|K|V row stride
#define KOFF_    4096          // K offset within fused row
#define VOFF_    5120          // V offset within fused row
#define SCALE_ 0.08838834764831845f

// async global->LDS, 16B/lane; LDS dest = wave-uniform base + lane*16
__device__ __forceinline__ void lds_cp16(void* lds, const void* g) {
  __builtin_amdgcn_global_load_lds(
      (const __attribute__((address_space(1))) void*)g,
      (__attribute__((address_space(3))) void*)lds, 16, 0, 0);
}

// ---------------------------------------------------------------------------
// fp32 -> bf16 elementwise convert (hidden pre-pass). 8 elems/thread.
// ---------------------------------------------------------------------------
__global__ void cvt_f32_bf16(const float* __restrict__ in, bf16* __restrict__ out,
                             long n) {
  const long i = ((long)blockIdx.x * blockDim.x + threadIdx.x) * 8;
  if (i >= n) return;
  float4 a = *(const float4*)(in + i);
  float4 b = *(const float4*)(in + i + 4);
  short8 cv;
  bf16 h;
  h = __float2bfloat16(a.x); cv[0] = *(short*)&h;
  h = __float2bfloat16(a.y); cv[1] = *(short*)&h;
  h = __float2bfloat16(a.z); cv[2] = *(short*)&h;
  h = __float2bfloat16(a.w); cv[3] = *(short*)&h;
  h = __float2bfloat16(b.x); cv[4] = *(short*)&h;
  h = __float2bfloat16(b.y); cv[5] = *(short*)&h;
  h = __float2bfloat16(b.z); cv[6] = *(short*)&h;
  h = __float2bfloat16(b.w); cv[7] = *(short*)&h;
  *(short8*)(out + i) = cv;
}

// ---------------------------------------------------------------------------
// C = A @ Bt^T, all bf16, m97 structure: 128x128 tile, BK=32, 4 waves,
// global_load_lds width 16.
// ---------------------------------------------------------------------------
__global__ __launch_bounds__(256) void gemm_nt(const bf16* __restrict__ A,
                                               const bf16* __restrict__ Bt,
                                               bf16* __restrict__ C,
                                               int M, int N, int K) {
  __shared__ __align__(16) bf16 lA[128 * 32];
  __shared__ __align__(16) bf16 lB[128 * 32];
  const int tid  = threadIdx.x;
  const int wave = tid >> 6, lane = tid & 63;
  const int wm = wave >> 1, wn = wave & 1;
  const int quad = lane >> 4, l15 = lane & 15;
  const long m0 = (long)blockIdx.y * 128, n0 = (long)blockIdx.x * 128;
  const int srow = lane >> 2, scol = (lane & 3) * 8;
  f32x4 acc[4][4] = {};

  for (int k0 = 0; k0 < K; k0 += 32) {
    __syncthreads();
#pragma unroll
    for (int i = 0; i < 2; ++i) {
      const int c = wave * 2 + i;
      lds_cp16(&lA[c * 512], A  + (m0 + c * 16 + srow) * (long)K + k0 + scol);
      lds_cp16(&lB[c * 512], Bt + (n0 + c * 16 + srow) * (long)K + k0 + scol);
    }
    __syncthreads();
    short8 af[4], bq[4];
#pragma unroll
    for (int t = 0; t < 4; ++t)
      af[t] = *(const short8*)&lA[(wm * 64 + t * 16 + l15) * 32 + quad * 8];
#pragma unroll
    for (int t = 0; t < 4; ++t)
      bq[t] = *(const short8*)&lB[(wn * 64 + t * 16 + l15) * 32 + quad * 8];
#pragma unroll
    for (int tm = 0; tm < 4; ++tm)
#pragma unroll
      for (int tn = 0; tn < 4; ++tn)
        acc[tm][tn] = __builtin_amdgcn_mfma_f32_16x16x32_bf16(
            af[tm], bq[tn], acc[tm][tn], 0, 0, 0);
  }
#pragma unroll
  for (int tm = 0; tm < 4; ++tm)
#pragma unroll
    for (int tn = 0; tn < 4; ++tn)
#pragma unroll
      for (int r = 0; r < 4; ++r) {
        const long row = m0 + wm * 64 + tm * 16 + quad * 4 + r;
        const long col = n0 + wn * 64 + tn * 16 + l15;
        C[row * N + col] = __float2bfloat16(acc[tm][tn][r]);
      }
}

// Same, fp32 output (O-projection into d_out).
__global__ __launch_bounds__(256) void gemm_nt_f32(const bf16* __restrict__ A,
                                                   const bf16* __restrict__ Bt,
                                                   float* __restrict__ C,
                                                   int M, int N, int K) {
  __shared__ __align__(16) bf16 lA[128 * 32];
  __shared__ __align__(16) bf16 lB[128 * 32];
  const int tid  = threadIdx.x;
  const int wave = tid >> 6, lane = tid & 63;
  const int wm = wave >> 1, wn = wave & 1;
  const int quad = lane >> 4, l15 = lane & 15;
  const long m0 = (long)blockIdx.y * 128, n0 = (long)blockIdx.x * 128;
  const int srow = lane >> 2, scol = (lane & 3) * 8;
  f32x4 acc[4][4] = {};

  for (int k0 = 0; k0 < K; k0 += 32) {
    __syncthreads();
#pragma unroll
    for (int i = 0; i < 2; ++i) {
      const int c = wave * 2 + i;
      lds_cp16(&lA[c * 512], A  + (m0 + c * 16 + srow) * (long)K + k0 + scol);
      lds_cp16(&lB[c * 512], Bt + (n0 + c * 16 + srow) * (long)K + k0 + scol);
    }
    __syncthreads();
    short8 af[4], bq[4];
#pragma unroll
    for (int t = 0; t < 4; ++t)
      af[t] = *(const short8*)&lA[(wm * 64 + t * 16 + l15) * 32 + quad * 8];
#pragma unroll
    for (int t = 0; t < 4; ++t)
      bq[t] = *(const short8*)&lB[(wn * 64 + t * 16 + l15) * 32 + quad * 8];
#pragma unroll
    for (int tm = 0; tm < 4; ++tm)
#pragma unroll
      for (int tn = 0; tn < 4; ++tn)
        acc[tm][tn] = __builtin_amdgcn_mfma_f32_16x16x32_bf16(
            af[tm], bq[tn], acc[tm][tn], 0, 0, 0);
  }
#pragma unroll
  for (int tm = 0; tm < 4; ++tm)
#pragma unroll
    for (int tn = 0; tn < 4; ++tn)
#pragma unroll
      for (int r = 0; r < 4; ++r) {
        const long row = m0 + wm * 64 + tm * 16 + quad * 4 + r;
        const long col = n0 + wn * 64 + tn * 16 + l15;
        C[row * N + col] = acc[tm][tn][r];
      }
}

// ---------------------------------------------------------------------------
// out bf16 (cols, rows) = convert(in fp32 (rows, cols)) transposed.
// ---------------------------------------------------------------------------
__global__ void transpose_f32_bf16(const float* __restrict__ in,
                                   bf16* __restrict__ out, int rows, int cols) {
  __shared__ bf16 t[32][33];
  const int c0 = blockIdx.x * 32, r0 = blockIdx.y * 32;
  const int tx = threadIdx.x, ty = threadIdx.y;
#pragma unroll
  for (int i = 0; i < 4; ++i)
    t[ty + i * 8][tx] =
        __float2bfloat16(in[(long)(r0 + ty + i * 8) * cols + c0 + tx]);
  __syncthreads();
#pragma unroll
  for (int i = 0; i < 4; ++i)
    out[(long)(c0 + ty + i * 8) * rows + r0 + tx] = t[tx][ty + i * 8];
}

// V slice of fused QKV (b,s,6144) -> VT (b,kv,d,s)
__global__ void v_transpose(const bf16* __restrict__ QKV, bf16* __restrict__ VT) {
  __shared__ bf16 t[32][33];
  const int z = blockIdx.z;              // b*8+kv
  const int b = z >> 3, kv = z & 7;
  const int d0 = blockIdx.x * 32, s0 = blockIdx.y * 32;
  const int tx = threadIdx.x, ty = threadIdx.y;
#pragma unroll
  for (int i = 0; i < 4; ++i)
    t[ty + i * 8][tx] =
        QKV[(long)(b * S_ + s0 + ty + i * 8) * QKVSTR_ + VOFF_ + kv * HD_ + d0 + tx];
  __syncthreads();
#pragma unroll
  for (int i = 0; i < 4; ++i)
    VT[((long)z * HD_ + d0 + ty + i * 8) * S_ + s0 + tx] = t[tx][ty + i * 8];
}

// RoPE in-place on bf16 rows of given stride at column offset; cos/sin fp32.
__global__ void rope_kernel(bf16* __restrict__ x, const float* __restrict__ cosb,
                            const float* __restrict__ sinb, int nheads,
                            int stride, int off) {
  const int idx = blockIdx.x * blockDim.x + threadIdx.x;
  const int d  = idx & 63;
  const int h  = (idx >> 6) % nheads;
  const int bs = idx / (64 * nheads);
  if (bs >= B_ * S_) return;
  const long base = (long)bs * stride + off + h * HD_;
  const float x1 = __bfloat162float(x[base + d]);
  const float x2 = __bfloat162float(x[base + d + 64]);
  const float c1 = cosb[(long)bs * HD_ + d];
  const float c2 = cosb[(long)bs * HD_ + d + 64];
  const float s1 = sinb[(long)bs * HD_ + d];
  const float s2 = sinb[(long)bs * HD_ + d + 64];
  x[base + d]      = __float2bfloat16(x1 * c1 - x2 * s1);
  x[base + d + 64] = __float2bfloat16(x2 * c2 + x1 * s2);
}

// ---------------------------------------------------------------------------
// Flash attention v3: butterfly-paired q-tiles for uniform block work.
// Block bx handles qt=bx then qt=15-bx -> every block runs exactly 36 kv-tile
// iterations. BM=128 (32 q rows/wave), BN=64, Q in registers, no-max softmax,
// deferred l-reduction, global_load_lds staging.
// QKV fused (b,s,6144); VT (b,kv,d,s) -> ctx (b,s,h,d) stride 4096.
// ---------------------------------------------------------------------------
__global__ __launch_bounds__(256, 2) void attn_fwd(const bf16* __restrict__ QKV,
                                                   const bf16* __restrict__ VT,
                                                   bf16* __restrict__ ctx) {
  __shared__ __align__(16) bf16 lK[64 * 128];   // 4 slabs of 64x32 (rows = kv)
  __shared__ __align__(16) bf16 lV[128 * 64];   // 2 slabs of 128x32 (rows = d)
  __shared__ __align__(16) bf16 lP[128 * 64];   // 2 slabs of 128x32 (rows = q)
  const int tid  = threadIdx.x;
  const int wave = tid >> 6, lane = tid & 63;
  const int quad = lane >> 4, l15 = lane & 15;
  const int srow = lane >> 2, scol = (lane & 3) * 8;
  const int bh = blockIdx.y;
  const int b = bh >> 5, h = bh & 31, kv = h >> 2;
  const long qbase = (long)b * S_ * QKVSTR_ + h * HD_;
  const long kbase = (long)b * S_ * QKVSTR_ + KOFF_ + kv * HD_;
  const long vbase = (long)(b * NKV_ + kv) * HD_ * S_;
  const long cbase = (long)b * S_ * QSTRIDE_ + h * HD_;

  for (int pass = 0; pass < 2; ++pass) {
    const int qt = pass ? 15 - (int)blockIdx.x : (int)blockIdx.x;
    const int q0 = qt * 128;

    // Q fragments in registers: wave covers rows [wave*32, wave*32+32)
    short8 qf[2][4];
#pragma unroll
    for (int mi = 0; mi < 2; ++mi)
#pragma unroll
      for (int kc = 0; kc < 4; ++kc)
        qf[mi][kc] = *(const short8*)(
            QKV + qbase + (long)(q0 + wave * 32 + mi * 16 + l15) * QKVSTR_ +
            kc * 32 + quad * 8);

    float lp[2][4] = {};   // per-lane partial row-sums (mi, r)
    f32x4 o[2][8] = {};

    const int nkt = 2 * qt + 2;  // kv tiles 0 .. (q0+127)/64
    for (int kt = 0; kt < nkt; ++kt) {
      const int k0 = kt * 64;
      __syncthreads();  // prev iter fully consumed lK/lV (and prev pass done)
#pragma unroll
      for (int i = 0; i < 4; ++i) {
        const int c = wave * 4 + i;
        lds_cp16(&lK[c * 512],
                 QKV + kbase + (long)(k0 + (c & 3) * 16 + srow) * QKVSTR_ +
                 (c >> 2) * 32 + scol);
        lds_cp16(&lV[c * 512],
                 VT + vbase + (long)((c & 7) * 16 + srow) * S_ + k0 +
                 (c >> 3) * 32 + scol);
      }
      __syncthreads();

      // S = Q K^T : 32 q rows per wave x 64 kv cols
      f32x4 sc[2][4] = {};
#pragma unroll
      for (int kc = 0; kc < 4; ++kc) {
        short8 kb[4];
#pragma unroll
        for (int j = 0; j < 4; ++j)
          kb[j] = *(const short8*)&lK[kc * 2048 + (j * 16 + l15) * 32 + quad * 8];
#pragma unroll
        for (int mi = 0; mi < 2; ++mi)
#pragma unroll
          for (int j = 0; j < 4; ++j)
            sc[mi][j] = __builtin_amdgcn_mfma_f32_16x16x32_bf16(
                qf[mi][kc], kb[j], sc[mi][j], 0, 0, 0);
      }

      // no-max softmax: p = mask ? 0 : exp(s*scale); accumulate per-lane l.
#pragma unroll
      for (int mi = 0; mi < 2; ++mi)
#pragma unroll
        for (int r = 0; r < 4; ++r) {
          const int qg = q0 + wave * 32 + mi * 16 + quad * 4 + r;
          const int rloc = wave * 32 + mi * 16 + quad * 4 + r;
#pragma unroll
          for (int j = 0; j < 4; ++j) {
            const int kg = k0 + j * 16 + l15;
            const float p = (kg <= qg) ? __expf(sc[mi][j][r] * SCALE_) : 0.f;
            lp[mi][r] += p;
            const int col = j * 16 + l15;
            lP[(col >> 5) * 4096 + rloc * 32 + (col & 31)] = __float2bfloat16(p);
          }
        }
      __syncthreads();  // P visible; lV still valid until next top barrier

      // O += P @ V
#pragma unroll
      for (int kc = 0; kc < 2; ++kc) {
        short8 pa[2];
#pragma unroll
        for (int mi = 0; mi < 2; ++mi)
          pa[mi] = *(const short8*)&lP[kc * 4096 + (wave * 32 + mi * 16 + l15) * 32 + quad * 8];
#pragma unroll
        for (int n = 0; n < 8; ++n) {
          const short8 vb = *(const short8*)&lV[kc * 4096 + (n * 16 + l15) * 32 + quad * 8];
#pragma unroll
          for (int mi = 0; mi < 2; ++mi)
            o[mi][n] = __builtin_amdgcn_mfma_f32_16x16x32_bf16(
                pa[mi], vb, o[mi][n], 0, 0, 0);
        }
      }
    }

    // epilogue: reduce l across the 16 lanes sharing each row, then O/l -> ctx
#pragma unroll
    for (int mi = 0; mi < 2; ++mi)
#pragma unroll
      for (int r = 0; r < 4; ++r) {
        float l = lp[mi][r];
#pragma unroll
        for (int off = 1; off < 16; off <<= 1)
          l += __shfl_xor(l, off, 64);
        const float inv = 1.f / l;
        const long row = q0 + wave * 32 + mi * 16 + quad * 4 + r;
#pragma unroll
        for (int n = 0; n < 8; ++n)
          ctx[cbase + row * QSTRIDE_ + n * 16 + l15] =
              __float2bfloat16(o[mi][n][r] * inv);
      }
  }
}

// ---------------------------------------------------------------------------
// Buffers (ws = 41,943,040 bf16 elems = 80 MiB, same budget as round 5):
//   ws: hiddenB [0,16.78M)  -> ctx overlays after QKV GEMM
//       slotT   [16.78M, 41.94M): fused wq|wk|wv ^T (25.17M) -> woT (16.78M)
//       VTb overlays slotT tail at [33.55M, 37.75M) after QKV GEMM
//   d_out: QKVb bf16 [0, 25.17M) (50 MiB of the 64 MiB fp32 buffer);
//          dead before the final fp32 GEMM overwrites d_out.
// ---------------------------------------------------------------------------
extern "C" void kernel_launch(void* const* d_in, const int* in_sizes, int n_in,
                              void* d_out, int out_size, void* d_ws, size_t ws_size,
                              hipStream_t stream) {
  const float* hidden = (const float*)d_in[0];
  const float* cosb   = (const float*)d_in[1];
  const float* sinb   = (const float*)d_in[2];
  // d_in[3] attention_mask: pure causal triu(-1e9), computed analytically
  const float* wq = (const float*)d_in[4];
  const float* wk = (const float*)d_in[5];
  const float* wv = (const float*)d_in[6];
  const float* wo = (const float*)d_in[7];

  bf16* ws      = (bf16*)d_ws;
  bf16* hiddenB = ws;                        // 16.78M
  bf16* ctx     = ws;                        // overlays hiddenB after QKV GEMM
  bf16* slotT   = ws + 16777216;             // 25.17M (fused weights) -> woT
  bf16* VTb     = ws + 33554432;             // 4.19M overlay in slotT tail
  bf16* QKVb    = (bf16*)d_out;              // 25.17M scratch in d_out
  float* out    = (float*)d_out;

  const dim3 tb(32, 8);

  cvt_f32_bf16<<<8192, 256, 0, stream>>>(hidden, hiddenB, (long)B_ * S_ * HID_);

  // fused Q|K|V weight transpose into slotT (rows = 6144-wide N index)
  transpose_f32_bf16<<<dim3(128, 128), tb, 0, stream>>>(wq, slotT, HID_, 4096);
  transpose_f32_bf16<<<dim3(32, 128), tb, 0, stream>>>(wk, slotT + (long)KOFF_ * HID_, HID_, 1024);
  transpose_f32_bf16<<<dim3(32, 128), tb, 0, stream>>>(wv, slotT + (long)VOFF_ * HID_, HID_, 1024);

  // one fused QKV projection: (4096 x 6144 x 4096)
  gemm_nt<<<dim3(48, 32), 256, 0, stream>>>(hiddenB, slotT, QKVb, B_ * S_, QKVSTR_, HID_);

  rope_kernel<<<(B_ * S_ * NH_ * 64) / 256, 256, 0, stream>>>(QKVb, cosb, sinb, NH_, QKVSTR_, 0);
  rope_kernel<<<(B_ * S_ * NKV_ * 64) / 256, 256, 0, stream>>>(QKVb, cosb, sinb, NKV_, QKVSTR_, KOFF_);

  v_transpose<<<dim3(4, 64, B_ * NKV_), tb, 0, stream>>>(QKVb, VTb);

  attn_fwd<<<dim3(8, B_ * NH_), 256, 0, stream>>>(QKVb, VTb, ctx);

  // O projection (fp32 out)
  transpose_f32_bf16<<<dim3(128, 128), tb, 0, stream>>>(wo, slotT, QSTRIDE_, HID_);
  gemm_nt_f32<<<dim3(32, 32), 256, 0, stream>>>(ctx, slotT, out, B_ * S_, HID_, HID_);
}